// Round 4
// baseline (16373.917 us; speedup 1.0000x reference)
//
#include <hip/hip_runtime.h>
#include <math.h>

#define TT 4096
#define HH 1024
#define GC 7168   // 7*H gate columns
#define KK 33     // emb table rows (K+1)
#define NB 256    // blocks: block b owns output elements j in [4b, 4b+4)
#define NT 448    // 7 waves: wave g handles gate group g

// Device-global scratch (re-initialized by setup_kernel every launch)
__device__ float g_P[KK * GC];                // precomputed emb@W[0:H] + b_r per event type
__device__ unsigned long long g_hd64[2 * HH]; // stamped h_d: (stamp<<32)|float_bits, double-buffered by parity

// ---------------------------------------------------------------------------
// Setup: P[k][j] = b_r[j] + sum_i emb[k][i] * w_r[i][j]; init stamped buffers.
// ---------------------------------------------------------------------------
__global__ __launch_bounds__(256) void setup_kernel(const float* __restrict__ w_r,
                                                    const float* __restrict__ b_r,
                                                    const float* __restrict__ emb) {
  const int j = blockIdx.x * 256 + threadIdx.x;  // grid = 28 blocks -> j in [0,7168)
  if (j < 2 * HH) g_hd64[j] = 0ULL;  // stamp 0 everywhere; first wanted stamp is 1
  float acc[KK];
  const float bj = b_r[j];
#pragma unroll
  for (int k = 0; k < KK; ++k) acc[k] = bj;
  for (int i = 0; i < HH; ++i) {
    const float w = w_r[(size_t)i * GC + j];   // coalesced across threads
#pragma unroll
    for (int k = 0; k < KK; ++k) acc[k] = fmaf(emb[k * HH + i], w, acc[k]);  // emb: uniform loads
  }
#pragma unroll
  for (int k = 0; k < KK; ++k) g_P[k * GC + j] = acc[k];
}

// ---------------------------------------------------------------------------
// Main persistent kernel. One block per 4 hidden elements (all 7 gates local).
// Recurrent weights live in registers: thread (g, jj, r) holds
// w_r[1024 + 4r + 64k + d][g*1024 + 4b + jj] for k in [0,16), d in [0,4).
// Cross-block exchange: stamped 64-bit values via atomic exchange (RMW at the
// coherence point), polled by dedicated threads 64..319 with relaxed loads.
// Publisher lanes (tid<4) never poll; own values short-cut through LDS.
// ---------------------------------------------------------------------------
__global__ __launch_bounds__(NT) void ctlstm_kernel(const int* __restrict__ event,
                                                    const float* __restrict__ duration,
                                                    const float* __restrict__ w_r,
                                                    float* __restrict__ out) {
  __shared__ __align__(16) float hd_lds[HH];
  __shared__ float gred[7][4];   // post-activation gate values
  const int tid = threadIdx.x;
  const int b = blockIdx.x;
  const int g = tid >> 6;        // wave id = gate group 0..6
  const int l = tid & 63;
  const int jj = l & 3;          // which of the block's 4 columns in this group
  const int r = l >> 2;          // 16 row-chunks per column
  const int col = g * HH + 4 * b + jj;

  // One-time weight load into registers (64 floats/thread).
  float4 w4[16];
#pragma unroll
  for (int k = 0; k < 16; ++k) {
    const float* wp = w_r + (size_t)(HH + 4 * r + 64 * k) * GC + col;
    w4[k].x = wp[0];
    w4[k].y = wp[GC];
    w4[k].z = wp[2 * (size_t)GC];
    w4[k].w = wp[3 * (size_t)GC];
  }
  for (int i = tid; i < HH; i += NT) hd_lds[i] = 0.f;  // h_d(-1) = 0
  float c_st = 0.f, cb_st = 0.f;                       // state lives in tid<4

  // Poller assignment: threads 64..319 poll index p, p+256, p+512, p+768.
  const bool is_poller = (tid >= 64 && tid < 320);
  const int p = tid - 64;
  // Pre-mark this block's own 4 indices (4b..4b+3) as done (filled via LDS).
  unsigned self_mask = 0u;
  if (is_poller && ((p >> 2) == (b & 63))) self_mask = 1u << (b >> 6);

  // Prefetch step-0 operands.
  float pval = 0.f;
  if (l < 4) pval = g_P[event[0] * GC + col];  // includes bias
  float du = 0.f;
  if (tid < 4) du = duration[0];
  __syncthreads();

  for (int t = 0; t < TT; ++t) {
    const bool not_last = (t < TT - 1);
    const int ev_next = not_last ? event[t + 1] : 0;  // uniform scalar load, in flight during matvec

    // ---- Phase A: matvec h_d @ W  (registers x LDS) ----
    float acc = 0.f;
#pragma unroll
    for (int k = 0; k < 16; ++k) {
      const float4 h4 = *(const float4*)&hd_lds[4 * r + 64 * k];
      acc = fmaf(w4[k].x, h4.x, acc);
      acc = fmaf(w4[k].y, h4.y, acc);
      acc = fmaf(w4[k].z, h4.z, acc);
      acc = fmaf(w4[k].w, h4.w, acc);
    }
    // reduce 16 partials per column (r encoded in lane bits 2..5)
    acc += __shfl_xor(acc, 4);
    acc += __shfl_xor(acc, 8);
    acc += __shfl_xor(acc, 16);
    acc += __shfl_xor(acc, 32);
    if (l < 4) {
      float v = acc + pval;
      // Per-gate activation in parallel across the 7 gate-waves (wave-uniform branch).
      if (g == 2) v = tanhf(v);                                     // g_z
      else if (g == 6) v = fmaxf(v, 0.f) + log1pf(expf(-fabsf(v))); // softplus(g_dl)
      else v = 1.f / (1.f + expf(-v));                              // sigmoids
      gred[g][jj] = v;
    }
    __syncthreads();  // gred ready; hd_lds free for rewrite

    // Prefetch next step's g_P row (in flight during Phase B/C polling).
    if (not_last && l < 4) pval = g_P[ev_next * GC + col];

    // ---- Phase B (tid<4): short serial chain + publish ----
    if (tid < 4) {
      const float si = gred[0][tid], sf = gred[1][tid], tz = gred[2][tid];
      const float so = gred[3][tid], sib = gred[4][tid], sfb = gred[5][tid];
      const float sp = gred[6][tid];
      const float c_n = fmaf(sf, c_st, si * tz);
      const float cb_n = fmaf(sfb, cb_st, sib * tz);
      c_st = c_n;
      cb_st = cb_n;
      const float cd = fmaf(c_n - cb_n, expf(-sp * du), cb_n);
      const int j = 4 * b + tid;
      if (not_last) {
        const float hdv = so * tanhf(cd);  // publish FIRST (critical path)
        const unsigned long long pk =
            ((unsigned long long)(unsigned)(t + 1) << 32) | (unsigned long long)__float_as_uint(hdv);
        (void)__hip_atomic_exchange(&g_hd64[((t + 1) & 1) * HH + j], pk,
                                    __ATOMIC_RELAXED, __HIP_MEMORY_SCOPE_AGENT);
        hd_lds[j] = hdv;        // self short-cut: own values never round-trip L3
        du = duration[t + 1];   // prefetch next duration
      }
      // Off-critical-path output stores (publisher lanes are not pollers).
      const size_t o = (size_t)t * HH + j;
      out[o] = so * tanhf(c_n);                       // h_seq
      out[(size_t)TT * HH + o] = c_n;                 // c_seq
      out[2 * (size_t)TT * HH + o] = cb_n;            // c_bar_seq
      out[3 * (size_t)TT * HH + o] = so;              // o_seq
      out[4 * (size_t)TT * HH + o] = sp;              // delta_seq
    }

    // ---- Phase C: dedicated pollers fill hd_lds for step t+1 ----
    if (not_last && is_poller) {
      const unsigned want = (unsigned)(t + 1);
      const unsigned long long* buf = &g_hd64[((t + 1) & 1) * HH];
      unsigned done = self_mask;
      do {
        const unsigned long long v0 = __hip_atomic_load(&buf[p],       __ATOMIC_RELAXED, __HIP_MEMORY_SCOPE_AGENT);
        const unsigned long long v1 = __hip_atomic_load(&buf[p + 256], __ATOMIC_RELAXED, __HIP_MEMORY_SCOPE_AGENT);
        const unsigned long long v2 = __hip_atomic_load(&buf[p + 512], __ATOMIC_RELAXED, __HIP_MEMORY_SCOPE_AGENT);
        const unsigned long long v3 = __hip_atomic_load(&buf[p + 768], __ATOMIC_RELAXED, __HIP_MEMORY_SCOPE_AGENT);
        if (!(done & 1u) && (unsigned)(v0 >> 32) == want) { hd_lds[p]       = __uint_as_float((unsigned)v0); done |= 1u; }
        if (!(done & 2u) && (unsigned)(v1 >> 32) == want) { hd_lds[p + 256] = __uint_as_float((unsigned)v1); done |= 2u; }
        if (!(done & 4u) && (unsigned)(v2 >> 32) == want) { hd_lds[p + 512] = __uint_as_float((unsigned)v2); done |= 4u; }
        if (!(done & 8u) && (unsigned)(v3 >> 32) == want) { hd_lds[p + 768] = __uint_as_float((unsigned)v3); done |= 8u; }
      } while (done != 15u);
    }
    __syncthreads();  // hd_lds ready for next step
  }
}

extern "C" void kernel_launch(void* const* d_in, const int* in_sizes, int n_in,
                              void* d_out, int out_size, void* d_ws, size_t ws_size,
                              hipStream_t stream) {
  const int* event = (const int*)d_in[0];
  const float* duration = (const float*)d_in[1];
  const float* w_r = (const float*)d_in[2];
  const float* b_r = (const float*)d_in[3];
  const float* emb = (const float*)d_in[4];
  float* out = (float*)d_out;
  setup_kernel<<<GC / 256, 256, 0, stream>>>(w_r, b_r, emb);
  ctlstm_kernel<<<NB, NT, 0, stream>>>(event, duration, w_r, out);
}